// Round 1
// baseline (580.450 us; speedup 1.0000x reference)
//
#include <hip/hip_runtime.h>
#include <hip/hip_bf16.h>
#include <stdint.h>

#define H_ 12
#define D_ 32
#define N_ 49
#define C_ 384
#define B_TOT 2048
#define BH 24576            // B_TOT * H_
#define M_ROWS 100352       // B_TOT * N_
#define SCALE 0.17677669529663689f

typedef float f32x4 __attribute__((ext_vector_type(4)));
typedef __bf16 bf16x8 __attribute__((ext_vector_type(8)));
typedef unsigned short ushortx8 __attribute__((ext_vector_type(8)));

static __device__ __forceinline__ unsigned short f2bf(float f) {
  __bf16 b = (__bf16)f;
  return __builtin_bit_cast(unsigned short, b);
}

// ---------------------------------------------------------------------------
// K0: combined bias+mask table: comb[w][h][64][64], -1e30 at c>=49 (mask pad)
// ---------------------------------------------------------------------------
__global__ void build_comb(const float* __restrict__ mask,
                           const float* __restrict__ rpb,
                           const int* __restrict__ ridx,
                           float* __restrict__ comb) {
  const int h = blockIdx.x, w = blockIdx.y;
  float* cb = comb + (size_t)(w * H_ + h) * 4096;
  const float* mw = mask + (size_t)w * N_ * N_;
  for (int e = threadIdx.x; e < 4096; e += 256) {
    const int r = e >> 6, c = e & 63;
    float v;
    if (c >= N_) v = -1e30f;
    else if (r >= N_) v = 0.0f;
    else v = mw[r * N_ + c] + rpb[ridx[r * N_ + c] * H_ + h];
    cb[e] = v;
  }
}

// ---------------------------------------------------------------------------
// K1: QKV GEMM: qkv = x @ qkv_w.T + qkv_b ; write bf16 to [3][b][h][seq][d]
// A fp32 [100352][384], W fp32 [1152][384]. 128x128 tile, 4 waves (2x2).
// ---------------------------------------------------------------------------
__global__ __launch_bounds__(256, 2)
void qkv_gemm(const float* __restrict__ A, const float* __restrict__ W,
              const float* __restrict__ bias, unsigned short* __restrict__ qkv) {
  __shared__ unsigned short lA[2][128 * 40];
  __shared__ unsigned short lB[2][128 * 40];
  const int tid = threadIdx.x;
  const int bn = blockIdx.x, bm = blockIdx.y;
  const int lane = tid & 63, wv = tid >> 6;
  const int wm = wv >> 1, wn = wv & 1;
  const int lo = lane & 15, hi = lane >> 4;
  const int rowL = tid >> 3, kq = tid & 7;

  const float* Ab = A + (size_t)bm * 128 * 384;
  const float* Wb = W + (size_t)bn * 128 * 384;

  f32x4 acc[4][4];
#pragma unroll
  for (int i = 0; i < 4; i++)
#pragma unroll
    for (int j = 0; j < 4; j++)
#pragma unroll
      for (int r = 0; r < 4; r++) acc[i][j][r] = 0.0f;

  // stage kt=0
#pragma unroll
  for (int i = 0; i < 4; i++) {
    const int r = rowL + 32 * i;
    float4 av = *(const float4*)(Ab + (size_t)r * 384 + kq * 4);
    float4 bv = *(const float4*)(Wb + (size_t)r * 384 + kq * 4);
    ushort4 ap = { f2bf(av.x), f2bf(av.y), f2bf(av.z), f2bf(av.w) };
    ushort4 bp = { f2bf(bv.x), f2bf(bv.y), f2bf(bv.z), f2bf(bv.w) };
    *(ushort4*)&lA[0][r * 40 + kq * 4] = ap;
    *(ushort4*)&lB[0][r * 40 + kq * 4] = bp;
  }
  __syncthreads();

  int buf = 0;
  for (int kt = 0; kt < 12; kt++) {
    float4 avr[4], bvr[4];
    if (kt < 11) {
#pragma unroll
      for (int i = 0; i < 4; i++) {
        const int r = rowL + 32 * i;
        avr[i] = *(const float4*)(Ab + (size_t)r * 384 + (kt + 1) * 32 + kq * 4);
        bvr[i] = *(const float4*)(Wb + (size_t)r * 384 + (kt + 1) * 32 + kq * 4);
      }
    }
    bf16x8 af[4], bfm[4];
#pragma unroll
    for (int mt = 0; mt < 4; mt++)
      af[mt] = *(const bf16x8*)&lA[buf][(wm * 64 + mt * 16 + lo) * 40 + hi * 8];
#pragma unroll
    for (int nt = 0; nt < 4; nt++)
      bfm[nt] = *(const bf16x8*)&lB[buf][(wn * 64 + nt * 16 + lo) * 40 + hi * 8];
#pragma unroll
    for (int mt = 0; mt < 4; mt++)
#pragma unroll
      for (int nt = 0; nt < 4; nt++)
        acc[mt][nt] = __builtin_amdgcn_mfma_f32_16x16x32_bf16(af[mt], bfm[nt], acc[mt][nt], 0, 0, 0);
    if (kt < 11) {
#pragma unroll
      for (int i = 0; i < 4; i++) {
        const int r = rowL + 32 * i;
        ushort4 ap = { f2bf(avr[i].x), f2bf(avr[i].y), f2bf(avr[i].z), f2bf(avr[i].w) };
        ushort4 bp = { f2bf(bvr[i].x), f2bf(bvr[i].y), f2bf(bvr[i].z), f2bf(bvr[i].w) };
        *(ushort4*)&lA[buf ^ 1][r * 40 + kq * 4] = ap;
        *(ushort4*)&lB[buf ^ 1][r * 40 + kq * 4] = bp;
      }
    }
    __syncthreads();
    buf ^= 1;
  }

  // epilogue: scatter to qkv[which][b][h][seq][d] bf16, q scaled
#pragma unroll
  for (int nt = 0; nt < 4; nt++) {
    const int j = bn * 128 + wn * 64 + nt * 16 + lo;
    const float bj = bias[j];
    const int which = j / 384;
    const int rem = j - which * 384;
    const int h = rem >> 5, dd = rem & 31;
    const float mul = (which == 0) ? SCALE : 1.0f;
#pragma unroll
    for (int mt = 0; mt < 4; mt++) {
#pragma unroll
      for (int r = 0; r < 4; r++) {
        const int i = bm * 128 + wm * 64 + mt * 16 + hi * 4 + r;
        const int b = i / 49, sq = i - b * 49;
        const float val = (acc[mt][nt][r] + bj) * mul;
        qkv[((size_t)which * BH + (size_t)b * H_ + h) * (N_ * D_) + sq * D_ + dd] = f2bf(val);
      }
    }
  }
}

// ---------------------------------------------------------------------------
// K2: attention per (b,h). 1 wave. QK^T MFMA, +comb, softmax, P/V via LDS,
// PV MFMA. Writes probs fp32 (d_out) and attn@V bf16 (ws, [b*49+seq][h*32+d]).
// ---------------------------------------------------------------------------
__global__ __launch_bounds__(64, 2)
void attn_kernel(const unsigned short* __restrict__ qkv,
                 const float* __restrict__ comb,
                 float* __restrict__ probs,
                 unsigned short* __restrict__ av) {
  __shared__ unsigned short P[64 * 72];
  __shared__ unsigned short VT[32 * 72];
  const int lane = threadIdx.x;
  const int lo = lane & 15, hi = lane >> 4;
  const int h = blockIdx.x, b = blockIdx.y;

  const unsigned short* qp = qkv + (size_t)(b * H_ + h) * (N_ * D_);
  const unsigned short* kp = qp + (size_t)BH * (N_ * D_);
  const unsigned short* vp = kp + (size_t)BH * (N_ * D_);

  // zero VT (pad cols must be non-NaN)
  {
    unsigned int* vz = (unsigned int*)VT;
#pragma unroll
    for (int i = 0; i < 18; i++) vz[lane + 64 * i] = 0u;
  }
  __syncthreads();

  // q/k fragments (rows >=49 read adjacent plane: finite, masked later)
  bf16x8 aq[4], bk[4];
#pragma unroll
  for (int t = 0; t < 4; t++) {
    aq[t] = *(const bf16x8*)(qp + (t * 16 + lo) * D_ + hi * 8);
    bk[t] = *(const bf16x8*)(kp + (t * 16 + lo) * D_ + hi * 8);
  }
  f32x4 s[4][4];
#pragma unroll
  for (int mt = 0; mt < 4; mt++)
#pragma unroll
    for (int nt = 0; nt < 4; nt++) {
#pragma unroll
      for (int r = 0; r < 4; r++) s[mt][nt][r] = 0.0f;
      s[mt][nt] = __builtin_amdgcn_mfma_f32_16x16x32_bf16(aq[mt], bk[nt], s[mt][nt], 0, 0, 0);
    }

  // stage V transposed into VT[d][seq]
#pragma unroll
  for (int it = 0; it < 4; it++) {
    const int idx = it * 64 + lane;
    if (idx < 196) {
      const int sq = idx >> 2, ch = idx & 3;
      ushortx8 vv = *(const ushortx8*)(vp + sq * D_ + ch * 8);
#pragma unroll
      for (int jj = 0; jj < 8; jj++) VT[(ch * 8 + jj) * 72 + sq] = vv[jj];
    }
  }

  // + comb, softmax over c (c>=49 pre-masked with -1e30)
  const float* cb = comb + (size_t)((b & 63) * H_ + h) * 4096;
#pragma unroll
  for (int mt = 0; mt < 4; mt++) {
#pragma unroll
    for (int r = 0; r < 4; r++) {
      const int row = mt * 16 + hi * 4 + r;
      const float* crow = cb + row * 64 + lo;
      float v0 = s[mt][0][r] + crow[0];
      float v1 = s[mt][1][r] + crow[16];
      float v2 = s[mt][2][r] + crow[32];
      float v3 = s[mt][3][r] + crow[48];
      float m = fmaxf(fmaxf(v0, v1), fmaxf(v2, v3));
      m = fmaxf(m, __shfl_xor(m, 1));
      m = fmaxf(m, __shfl_xor(m, 2));
      m = fmaxf(m, __shfl_xor(m, 4));
      m = fmaxf(m, __shfl_xor(m, 8));
      v0 = __expf(v0 - m); v1 = __expf(v1 - m);
      v2 = __expf(v2 - m); v3 = __expf(v3 - m);
      float sum = v0 + v1 + v2 + v3;
      sum += __shfl_xor(sum, 1);
      sum += __shfl_xor(sum, 2);
      sum += __shfl_xor(sum, 4);
      sum += __shfl_xor(sum, 8);
      const float rinv = 1.0f / sum;
      s[mt][0][r] = v0 * rinv; s[mt][1][r] = v1 * rinv;
      s[mt][2][r] = v2 * rinv; s[mt][3][r] = v3 * rinv;
    }
  }

  // write probs (fp32) and P (bf16 LDS)
  const size_t pbase = (size_t)(b * H_ + h) * N_ * N_;
#pragma unroll
  for (int mt = 0; mt < 4; mt++) {
#pragma unroll
    for (int r = 0; r < 4; r++) {
      const int row = mt * 16 + hi * 4 + r;
      if (row < N_) {
#pragma unroll
        for (int nt = 0; nt < 4; nt++) {
          const int c = nt * 16 + lo;
          if (c < N_) probs[pbase + row * N_ + c] = s[mt][nt][r];
        }
      }
#pragma unroll
      for (int nt = 0; nt < 4; nt++)
        P[row * 72 + nt * 16 + lo] = f2bf(s[mt][nt][r]);
    }
  }
  __syncthreads();

  // PV: out[qr][dv] = sum_k P[qr][k] * VT[dv][k]
  f32x4 o[4][2];
#pragma unroll
  for (int mt = 0; mt < 4; mt++)
#pragma unroll
    for (int n2 = 0; n2 < 2; n2++)
#pragma unroll
      for (int r = 0; r < 4; r++) o[mt][n2][r] = 0.0f;
#pragma unroll
  for (int ks = 0; ks < 2; ks++) {
    bf16x8 pa[4], vb[2];
#pragma unroll
    for (int mt = 0; mt < 4; mt++)
      pa[mt] = *(const bf16x8*)&P[(mt * 16 + lo) * 72 + ks * 32 + hi * 8];
#pragma unroll
    for (int n2 = 0; n2 < 2; n2++)
      vb[n2] = *(const bf16x8*)&VT[(n2 * 16 + lo) * 72 + ks * 32 + hi * 8];
#pragma unroll
    for (int mt = 0; mt < 4; mt++)
#pragma unroll
      for (int n2 = 0; n2 < 2; n2++)
        o[mt][n2] = __builtin_amdgcn_mfma_f32_16x16x32_bf16(pa[mt], vb[n2], o[mt][n2], 0, 0, 0);
  }

  // store attn@V bf16 to ws: [b*49+row][h*32 + dv]
#pragma unroll
  for (int mt = 0; mt < 4; mt++) {
#pragma unroll
    for (int r = 0; r < 4; r++) {
      const int row = mt * 16 + hi * 4 + r;
      if (row < N_) {
#pragma unroll
        for (int n2 = 0; n2 < 2; n2++) {
          const int dv = n2 * 16 + lo;
          av[((size_t)b * N_ + row) * C_ + h * D_ + dv] = f2bf(o[mt][n2][r]);
        }
      }
    }
  }
}

// ---------------------------------------------------------------------------
// K3: proj GEMM: out = av @ proj_w.T + proj_b. A bf16 [100352][384],
// W fp32 [384][384], out fp32.
// ---------------------------------------------------------------------------
__global__ __launch_bounds__(256, 2)
void proj_gemm(const unsigned short* __restrict__ A, const float* __restrict__ W,
               const float* __restrict__ bias, float* __restrict__ out) {
  __shared__ unsigned short lA[2][128 * 40];
  __shared__ unsigned short lB[2][128 * 40];
  const int tid = threadIdx.x;
  const int bn = blockIdx.x, bm = blockIdx.y;
  const int lane = tid & 63, wv = tid >> 6;
  const int wm = wv >> 1, wn = wv & 1;
  const int lo = lane & 15, hi = lane >> 4;
  const int rowL = tid >> 3, kq = tid & 7;   // B staging (fp32)
  const int rowA = tid >> 2, ch = tid & 3;   // A staging (bf16)

  const unsigned short* Ab = A + (size_t)bm * 128 * 384;
  const float* Wb = W + (size_t)bn * 128 * 384;

  f32x4 acc[4][4];
#pragma unroll
  for (int i = 0; i < 4; i++)
#pragma unroll
    for (int j = 0; j < 4; j++)
#pragma unroll
      for (int r = 0; r < 4; r++) acc[i][j][r] = 0.0f;

#pragma unroll
  for (int i = 0; i < 2; i++) {
    const int r = rowA + 64 * i;
    *(uint4*)&lA[0][r * 40 + ch * 8] = *(const uint4*)(Ab + (size_t)r * 384 + ch * 8);
  }
#pragma unroll
  for (int i = 0; i < 4; i++) {
    const int r = rowL + 32 * i;
    float4 bv = *(const float4*)(Wb + (size_t)r * 384 + kq * 4);
    ushort4 bp = { f2bf(bv.x), f2bf(bv.y), f2bf(bv.z), f2bf(bv.w) };
    *(ushort4*)&lB[0][r * 40 + kq * 4] = bp;
  }
  __syncthreads();

  int buf = 0;
  for (int kt = 0; kt < 12; kt++) {
    uint4 avr[2];
    float4 bvr[4];
    if (kt < 11) {
#pragma unroll
      for (int i = 0; i < 2; i++) {
        const int r = rowA + 64 * i;
        avr[i] = *(const uint4*)(Ab + (size_t)r * 384 + (kt + 1) * 32 + ch * 8);
      }
#pragma unroll
      for (int i = 0; i < 4; i++) {
        const int r = rowL + 32 * i;
        bvr[i] = *(const float4*)(Wb + (size_t)r * 384 + (kt + 1) * 32 + kq * 4);
      }
    }
    bf16x8 af[4], bfm[4];
#pragma unroll
    for (int mt = 0; mt < 4; mt++)
      af[mt] = *(const bf16x8*)&lA[buf][(wm * 64 + mt * 16 + lo) * 40 + hi * 8];
#pragma unroll
    for (int nt = 0; nt < 4; nt++)
      bfm[nt] = *(const bf16x8*)&lB[buf][(wn * 64 + nt * 16 + lo) * 40 + hi * 8];
#pragma unroll
    for (int mt = 0; mt < 4; mt++)
#pragma unroll
      for (int nt = 0; nt < 4; nt++)
        acc[mt][nt] = __builtin_amdgcn_mfma_f32_16x16x32_bf16(af[mt], bfm[nt], acc[mt][nt], 0, 0, 0);
    if (kt < 11) {
#pragma unroll
      for (int i = 0; i < 2; i++) {
        const int r = rowA + 64 * i;
        *(uint4*)&lA[buf ^ 1][r * 40 + ch * 8] = avr[i];
      }
#pragma unroll
      for (int i = 0; i < 4; i++) {
        const int r = rowL + 32 * i;
        ushort4 bp = { f2bf(bvr[i].x), f2bf(bvr[i].y), f2bf(bvr[i].z), f2bf(bvr[i].w) };
        *(ushort4*)&lB[buf ^ 1][r * 40 + kq * 4] = bp;
      }
    }
    __syncthreads();
    buf ^= 1;
  }

#pragma unroll
  for (int nt = 0; nt < 4; nt++) {
    const int j = bn * 128 + wn * 64 + nt * 16 + lo;
    const float bj = bias[j];
#pragma unroll
    for (int mt = 0; mt < 4; mt++) {
#pragma unroll
      for (int r = 0; r < 4; r++) {
        const int i = bm * 128 + wm * 64 + mt * 16 + hi * 4 + r;
        out[(size_t)i * 384 + j] = acc[mt][nt][r] + bj;
      }
    }
  }
}

// ---------------------------------------------------------------------------
extern "C" void kernel_launch(void* const* d_in, const int* in_sizes, int n_in,
                              void* d_out, int out_size, void* d_ws, size_t ws_size,
                              hipStream_t stream) {
  const float* x      = (const float*)d_in[0];
  const float* mask   = (const float*)d_in[1];
  const float* qkv_w  = (const float*)d_in[2];
  const float* qkv_b  = (const float*)d_in[3];
  const float* proj_w = (const float*)d_in[4];
  const float* proj_b = (const float*)d_in[5];
  const float* rpb    = (const float*)d_in[6];
  const int*   ridx   = (const int*)d_in[7];

  unsigned short* qkv = (unsigned short*)d_ws;                 // 3*24576*1568 bf16
  unsigned short* av  = qkv + (size_t)3 * BH * N_ * D_;        // 100352*384 bf16
  float* comb = (float*)(av + (size_t)M_ROWS * C_);            // 768*4096 fp32
  float* out   = (float*)d_out;
  float* probs = out + (size_t)M_ROWS * C_;

  build_comb<<<dim3(H_, 64), 256, 0, stream>>>(mask, rpb, ridx, comb);
  qkv_gemm<<<dim3(9, 784), 256, 0, stream>>>(x, qkv_w, qkv_b, qkv);
  attn_kernel<<<dim3(H_, B_TOT), 64, 0, stream>>>(qkv, comb, probs, av);
  proj_gemm<<<dim3(3, 784), 256, 0, stream>>>(av, proj_w, proj_b, out);
}

// Round 2
// 557.175 us; speedup vs baseline: 1.0418x; 1.0418x over previous
//
#include <hip/hip_runtime.h>
#include <hip/hip_bf16.h>
#include <stdint.h>

#define H_ 12
#define D_ 32
#define N_ 49
#define C_ 384
#define B_TOT 2048
#define BH 24576            // B_TOT * H_
#define M_ROWS 100352       // B_TOT * N_
#define SCALE 0.17677669529663689f

typedef float f32x4 __attribute__((ext_vector_type(4)));
typedef __bf16 bf16x8 __attribute__((ext_vector_type(8)));
typedef unsigned short ushortx8 __attribute__((ext_vector_type(8)));

static __device__ __forceinline__ unsigned short f2bf(float f) {
  __bf16 b = (__bf16)f;
  return __builtin_bit_cast(unsigned short, b);
}

// ---------------------------------------------------------------------------
// K-1: fp32 -> bf16 cast, 8 elems/thread, grid-stride
// ---------------------------------------------------------------------------
__global__ void cast_bf16(const float* __restrict__ in,
                          unsigned short* __restrict__ out, int n8) {
  int i = blockIdx.x * blockDim.x + threadIdx.x;
  const int stride = gridDim.x * blockDim.x;
  for (; i < n8; i += stride) {
    float4 a = ((const float4*)in)[2 * i];
    float4 b = ((const float4*)in)[2 * i + 1];
    ushortx8 v;
    v[0] = f2bf(a.x); v[1] = f2bf(a.y); v[2] = f2bf(a.z); v[3] = f2bf(a.w);
    v[4] = f2bf(b.x); v[5] = f2bf(b.y); v[6] = f2bf(b.z); v[7] = f2bf(b.w);
    *(ushortx8*)&out[(size_t)i * 8] = v;
  }
}

// ---------------------------------------------------------------------------
// K0: combined bias+mask table: comb[w][h][64][64], -1e30 at c>=49 (mask pad)
// ---------------------------------------------------------------------------
__global__ void build_comb(const float* __restrict__ mask,
                           const float* __restrict__ rpb,
                           const int* __restrict__ ridx,
                           float* __restrict__ comb) {
  const int h = blockIdx.x, w = blockIdx.y;
  float* cb = comb + (size_t)(w * H_ + h) * 4096;
  const float* mw = mask + (size_t)w * N_ * N_;
  for (int e = threadIdx.x; e < 4096; e += 256) {
    const int r = e >> 6, c = e & 63;
    float v;
    if (c >= N_) v = -1e30f;
    else if (r >= N_) v = 0.0f;
    else v = mw[r * N_ + c] + rpb[ridx[r * N_ + c] * H_ + h];
    cb[e] = v;
  }
}

// ---------------------------------------------------------------------------
// K1: QKV GEMM (all-bf16 inputs): qkv = x @ qkv_w.T + qkv_b
// A bf16 [100352][384], W bf16 [1152][384]. 128x128 tile, 4 waves (2x2).
// Epilogue scatters bf16 to [3][b][h][seq][d], q scaled.
// ---------------------------------------------------------------------------
__global__ __launch_bounds__(256, 3)
void qkv_gemm(const unsigned short* __restrict__ A,
              const unsigned short* __restrict__ W,
              const float* __restrict__ bias, unsigned short* __restrict__ qkv) {
  __shared__ unsigned short lA[2][128 * 40];
  __shared__ unsigned short lB[2][128 * 40];
  const int tid = threadIdx.x;
  const int bn = blockIdx.x, bm = blockIdx.y;
  const int lane = tid & 63, wv = tid >> 6;
  const int wm = wv >> 1, wn = wv & 1;
  const int lo = lane & 15, hi = lane >> 4;
  // staging: 128 rows x 32 cols bf16 = 512 x 16B chunks; 2 chunks/thread
  const int r0 = tid >> 2, r1 = r0 + 64;
  const int off = (tid & 3) * 8;

  const unsigned short* Ab = A + (size_t)bm * 128 * 384;
  const unsigned short* Wb = W + (size_t)bn * 128 * 384;

  f32x4 acc[4][4];
#pragma unroll
  for (int i = 0; i < 4; i++)
#pragma unroll
    for (int j = 0; j < 4; j++)
#pragma unroll
      for (int r = 0; r < 4; r++) acc[i][j][r] = 0.0f;

  // stage kt=0
  *(uint4*)&lA[0][r0 * 40 + off] = *(const uint4*)(Ab + r0 * 384 + off);
  *(uint4*)&lA[0][r1 * 40 + off] = *(const uint4*)(Ab + r1 * 384 + off);
  *(uint4*)&lB[0][r0 * 40 + off] = *(const uint4*)(Wb + r0 * 384 + off);
  *(uint4*)&lB[0][r1 * 40 + off] = *(const uint4*)(Wb + r1 * 384 + off);
  __syncthreads();

  int buf = 0;
  for (int kt = 0; kt < 12; kt++) {
    uint4 pa0, pa1, pb0, pb1;
    if (kt < 11) {
      const int kc = (kt + 1) * 32 + off;
      pa0 = *(const uint4*)(Ab + r0 * 384 + kc);
      pa1 = *(const uint4*)(Ab + r1 * 384 + kc);
      pb0 = *(const uint4*)(Wb + r0 * 384 + kc);
      pb1 = *(const uint4*)(Wb + r1 * 384 + kc);
    }
    bf16x8 af[4], bfm[4];
#pragma unroll
    for (int mt = 0; mt < 4; mt++)
      af[mt] = *(const bf16x8*)&lA[buf][(wm * 64 + mt * 16 + lo) * 40 + hi * 8];
#pragma unroll
    for (int nt = 0; nt < 4; nt++)
      bfm[nt] = *(const bf16x8*)&lB[buf][(wn * 64 + nt * 16 + lo) * 40 + hi * 8];
#pragma unroll
    for (int mt = 0; mt < 4; mt++)
#pragma unroll
      for (int nt = 0; nt < 4; nt++)
        acc[mt][nt] = __builtin_amdgcn_mfma_f32_16x16x32_bf16(af[mt], bfm[nt], acc[mt][nt], 0, 0, 0);
    if (kt < 11) {
      *(uint4*)&lA[buf ^ 1][r0 * 40 + off] = pa0;
      *(uint4*)&lA[buf ^ 1][r1 * 40 + off] = pa1;
      *(uint4*)&lB[buf ^ 1][r0 * 40 + off] = pb0;
      *(uint4*)&lB[buf ^ 1][r1 * 40 + off] = pb1;
    }
    __syncthreads();
    buf ^= 1;
  }

  // epilogue: scatter to qkv[which][b][h][seq][d] bf16, q scaled
#pragma unroll
  for (int nt = 0; nt < 4; nt++) {
    const int j = bn * 128 + wn * 64 + nt * 16 + lo;
    const float bj = bias[j];
    const int which = j / 384;
    const int rem = j - which * 384;
    const int h = rem >> 5, dd = rem & 31;
    const float mul = (which == 0) ? SCALE : 1.0f;
#pragma unroll
    for (int mt = 0; mt < 4; mt++) {
#pragma unroll
      for (int r = 0; r < 4; r++) {
        const int i = bm * 128 + wm * 64 + mt * 16 + hi * 4 + r;
        const int b = i / 49, sq = i - b * 49;
        const float val = (acc[mt][nt][r] + bj) * mul;
        qkv[((size_t)which * BH + (size_t)b * H_ + h) * (N_ * D_) + sq * D_ + dd] = f2bf(val);
      }
    }
  }
}

// ---------------------------------------------------------------------------
// K2: attention per (b,h). 1 wave. QK^T MFMA, +comb, softmax, P/V via LDS,
// PV MFMA. Writes probs fp32 (d_out) and attn@V bf16 (ws, [b*49+seq][h*32+d]).
// ---------------------------------------------------------------------------
__global__ __launch_bounds__(64, 2)
void attn_kernel(const unsigned short* __restrict__ qkv,
                 const float* __restrict__ comb,
                 float* __restrict__ probs,
                 unsigned short* __restrict__ av) {
  __shared__ unsigned short P[64 * 72];
  __shared__ unsigned short VT[32 * 72];
  const int lane = threadIdx.x;
  const int lo = lane & 15, hi = lane >> 4;
  const int h = blockIdx.x, b = blockIdx.y;

  const unsigned short* qp = qkv + (size_t)(b * H_ + h) * (N_ * D_);
  const unsigned short* kp = qp + (size_t)BH * (N_ * D_);
  const unsigned short* vp = kp + (size_t)BH * (N_ * D_);

  // zero VT (pad cols must be non-NaN)
  {
    unsigned int* vz = (unsigned int*)VT;
#pragma unroll
    for (int i = 0; i < 18; i++) vz[lane + 64 * i] = 0u;
  }
  __syncthreads();

  // q/k fragments (rows >=49 read adjacent plane: finite, masked later)
  bf16x8 aq[4], bk[4];
#pragma unroll
  for (int t = 0; t < 4; t++) {
    aq[t] = *(const bf16x8*)(qp + (t * 16 + lo) * D_ + hi * 8);
    bk[t] = *(const bf16x8*)(kp + (t * 16 + lo) * D_ + hi * 8);
  }
  f32x4 s[4][4];
#pragma unroll
  for (int mt = 0; mt < 4; mt++)
#pragma unroll
    for (int nt = 0; nt < 4; nt++) {
#pragma unroll
      for (int r = 0; r < 4; r++) s[mt][nt][r] = 0.0f;
      s[mt][nt] = __builtin_amdgcn_mfma_f32_16x16x32_bf16(aq[mt], bk[nt], s[mt][nt], 0, 0, 0);
    }

  // stage V transposed into VT[d][seq]
#pragma unroll
  for (int it = 0; it < 4; it++) {
    const int idx = it * 64 + lane;
    if (idx < 196) {
      const int sq = idx >> 2, ch = idx & 3;
      ushortx8 vv = *(const ushortx8*)(vp + sq * D_ + ch * 8);
#pragma unroll
      for (int jj = 0; jj < 8; jj++) VT[(ch * 8 + jj) * 72 + sq] = vv[jj];
    }
  }

  // + comb, softmax over c (c>=49 pre-masked with -1e30)
  const float* cb = comb + (size_t)((b & 63) * H_ + h) * 4096;
#pragma unroll
  for (int mt = 0; mt < 4; mt++) {
#pragma unroll
    for (int r = 0; r < 4; r++) {
      const int row = mt * 16 + hi * 4 + r;
      const float* crow = cb + row * 64 + lo;
      float v0 = s[mt][0][r] + crow[0];
      float v1 = s[mt][1][r] + crow[16];
      float v2 = s[mt][2][r] + crow[32];
      float v3 = s[mt][3][r] + crow[48];
      float m = fmaxf(fmaxf(v0, v1), fmaxf(v2, v3));
      m = fmaxf(m, __shfl_xor(m, 1));
      m = fmaxf(m, __shfl_xor(m, 2));
      m = fmaxf(m, __shfl_xor(m, 4));
      m = fmaxf(m, __shfl_xor(m, 8));
      v0 = __expf(v0 - m); v1 = __expf(v1 - m);
      v2 = __expf(v2 - m); v3 = __expf(v3 - m);
      float sum = v0 + v1 + v2 + v3;
      sum += __shfl_xor(sum, 1);
      sum += __shfl_xor(sum, 2);
      sum += __shfl_xor(sum, 4);
      sum += __shfl_xor(sum, 8);
      const float rinv = 1.0f / sum;
      s[mt][0][r] = v0 * rinv; s[mt][1][r] = v1 * rinv;
      s[mt][2][r] = v2 * rinv; s[mt][3][r] = v3 * rinv;
    }
  }

  // write probs (fp32) and P (bf16 LDS)
  const size_t pbase = (size_t)(b * H_ + h) * N_ * N_;
#pragma unroll
  for (int mt = 0; mt < 4; mt++) {
#pragma unroll
    for (int r = 0; r < 4; r++) {
      const int row = mt * 16 + hi * 4 + r;
      if (row < N_) {
#pragma unroll
        for (int nt = 0; nt < 4; nt++) {
          const int c = nt * 16 + lo;
          if (c < N_) probs[pbase + row * N_ + c] = s[mt][nt][r];
        }
      }
#pragma unroll
      for (int nt = 0; nt < 4; nt++)
        P[row * 72 + nt * 16 + lo] = f2bf(s[mt][nt][r]);
    }
  }
  __syncthreads();

  // PV: out[qr][dv] = sum_k P[qr][k] * VT[dv][k]
  f32x4 o[4][2];
#pragma unroll
  for (int mt = 0; mt < 4; mt++)
#pragma unroll
    for (int n2 = 0; n2 < 2; n2++)
#pragma unroll
      for (int r = 0; r < 4; r++) o[mt][n2][r] = 0.0f;
#pragma unroll
  for (int ks = 0; ks < 2; ks++) {
    bf16x8 pa[4], vb[2];
#pragma unroll
    for (int mt = 0; mt < 4; mt++)
      pa[mt] = *(const bf16x8*)&P[(mt * 16 + lo) * 72 + ks * 32 + hi * 8];
#pragma unroll
    for (int n2 = 0; n2 < 2; n2++)
      vb[n2] = *(const bf16x8*)&VT[(n2 * 16 + lo) * 72 + ks * 32 + hi * 8];
#pragma unroll
    for (int mt = 0; mt < 4; mt++)
#pragma unroll
      for (int n2 = 0; n2 < 2; n2++)
        o[mt][n2] = __builtin_amdgcn_mfma_f32_16x16x32_bf16(pa[mt], vb[n2], o[mt][n2], 0, 0, 0);
  }

  // store attn@V bf16 to ws: [b*49+row][h*32 + dv]
#pragma unroll
  for (int mt = 0; mt < 4; mt++) {
#pragma unroll
    for (int r = 0; r < 4; r++) {
      const int row = mt * 16 + hi * 4 + r;
      if (row < N_) {
#pragma unroll
        for (int n2 = 0; n2 < 2; n2++) {
          const int dv = n2 * 16 + lo;
          av[((size_t)b * N_ + row) * C_ + h * D_ + dv] = f2bf(o[mt][n2][r]);
        }
      }
    }
  }
}

// ---------------------------------------------------------------------------
// K3: proj GEMM: out = av @ proj_w.T + proj_b. A bf16 [100352][384],
// W bf16 [384][384], out fp32.
// ---------------------------------------------------------------------------
__global__ __launch_bounds__(256, 3)
void proj_gemm(const unsigned short* __restrict__ A,
               const unsigned short* __restrict__ W,
               const float* __restrict__ bias, float* __restrict__ out) {
  __shared__ unsigned short lA[2][128 * 40];
  __shared__ unsigned short lB[2][128 * 40];
  const int tid = threadIdx.x;
  const int bn = blockIdx.x, bm = blockIdx.y;
  const int lane = tid & 63, wv = tid >> 6;
  const int wm = wv >> 1, wn = wv & 1;
  const int lo = lane & 15, hi = lane >> 4;
  const int r0 = tid >> 2, r1 = r0 + 64;
  const int off = (tid & 3) * 8;

  const unsigned short* Ab = A + (size_t)bm * 128 * 384;
  const unsigned short* Wb = W + (size_t)bn * 128 * 384;

  f32x4 acc[4][4];
#pragma unroll
  for (int i = 0; i < 4; i++)
#pragma unroll
    for (int j = 0; j < 4; j++)
#pragma unroll
      for (int r = 0; r < 4; r++) acc[i][j][r] = 0.0f;

  *(uint4*)&lA[0][r0 * 40 + off] = *(const uint4*)(Ab + r0 * 384 + off);
  *(uint4*)&lA[0][r1 * 40 + off] = *(const uint4*)(Ab + r1 * 384 + off);
  *(uint4*)&lB[0][r0 * 40 + off] = *(const uint4*)(Wb + r0 * 384 + off);
  *(uint4*)&lB[0][r1 * 40 + off] = *(const uint4*)(Wb + r1 * 384 + off);
  __syncthreads();

  int buf = 0;
  for (int kt = 0; kt < 12; kt++) {
    uint4 pa0, pa1, pb0, pb1;
    if (kt < 11) {
      const int kc = (kt + 1) * 32 + off;
      pa0 = *(const uint4*)(Ab + r0 * 384 + kc);
      pa1 = *(const uint4*)(Ab + r1 * 384 + kc);
      pb0 = *(const uint4*)(Wb + r0 * 384 + kc);
      pb1 = *(const uint4*)(Wb + r1 * 384 + kc);
    }
    bf16x8 af[4], bfm[4];
#pragma unroll
    for (int mt = 0; mt < 4; mt++)
      af[mt] = *(const bf16x8*)&lA[buf][(wm * 64 + mt * 16 + lo) * 40 + hi * 8];
#pragma unroll
    for (int nt = 0; nt < 4; nt++)
      bfm[nt] = *(const bf16x8*)&lB[buf][(wn * 64 + nt * 16 + lo) * 40 + hi * 8];
#pragma unroll
    for (int mt = 0; mt < 4; mt++)
#pragma unroll
      for (int nt = 0; nt < 4; nt++)
        acc[mt][nt] = __builtin_amdgcn_mfma_f32_16x16x32_bf16(af[mt], bfm[nt], acc[mt][nt], 0, 0, 0);
    if (kt < 11) {
      *(uint4*)&lA[buf ^ 1][r0 * 40 + off] = pa0;
      *(uint4*)&lA[buf ^ 1][r1 * 40 + off] = pa1;
      *(uint4*)&lB[buf ^ 1][r0 * 40 + off] = pb0;
      *(uint4*)&lB[buf ^ 1][r1 * 40 + off] = pb1;
    }
    __syncthreads();
    buf ^= 1;
  }

#pragma unroll
  for (int nt = 0; nt < 4; nt++) {
    const int j = bn * 128 + wn * 64 + nt * 16 + lo;
    const float bj = bias[j];
#pragma unroll
    for (int mt = 0; mt < 4; mt++) {
#pragma unroll
      for (int r = 0; r < 4; r++) {
        const int i = bm * 128 + wm * 64 + mt * 16 + hi * 4 + r;
        out[(size_t)i * 384 + j] = acc[mt][nt][r] + bj;
      }
    }
  }
}

// ---------------------------------------------------------------------------
extern "C" void kernel_launch(void* const* d_in, const int* in_sizes, int n_in,
                              void* d_out, int out_size, void* d_ws, size_t ws_size,
                              hipStream_t stream) {
  const float* x      = (const float*)d_in[0];
  const float* mask   = (const float*)d_in[1];
  const float* qkv_w  = (const float*)d_in[2];
  const float* qkv_b  = (const float*)d_in[3];
  const float* proj_w = (const float*)d_in[4];
  const float* proj_b = (const float*)d_in[5];
  const float* rpb    = (const float*)d_in[6];
  const int*   ridx   = (const int*)d_in[7];

  // ws layout (bytes):
  //   qkv bf16:   3*BH*1568 shorts          = 231.2 MB
  //   av  bf16:   M_ROWS*C_ shorts (ALIASED with x_bf16) = 77.1 MB
  //   comb fp32:  768*4096 floats           = 12.6 MB
  //   wq  bf16:   1152*384 shorts           = 0.88 MB
  //   wp  bf16:   384*384 shorts            = 0.29 MB
  unsigned short* qkv   = (unsigned short*)d_ws;
  unsigned short* av    = qkv + (size_t)3 * BH * N_ * D_;   // alias: x_bf16
  unsigned short* x_bf  = av;
  float* comb           = (float*)(av + (size_t)M_ROWS * C_);
  unsigned short* wq_bf = (unsigned short*)(comb + 768 * 4096);
  unsigned short* wp_bf = wq_bf + 1152 * 384;
  float* out   = (float*)d_out;
  float* probs = out + (size_t)M_ROWS * C_;

  cast_bf16<<<2048, 256, 0, stream>>>(x, x_bf, M_ROWS * C_ / 8);
  cast_bf16<<<216, 256, 0, stream>>>(qkv_w, wq_bf, 1152 * 384 / 8);
  cast_bf16<<<72, 256, 0, stream>>>(proj_w, wp_bf, 384 * 384 / 8);
  build_comb<<<dim3(H_, 64), 256, 0, stream>>>(mask, rpb, ridx, comb);
  qkv_gemm<<<dim3(9, 784), 256, 0, stream>>>(x_bf, wq_bf, qkv_b, qkv);
  attn_kernel<<<dim3(H_, B_TOT), 64, 0, stream>>>(qkv, comb, probs, av);
  proj_gemm<<<dim3(3, 784), 256, 0, stream>>>(av, wp_bf, proj_b, out);
}

// Round 3
// 480.285 us; speedup vs baseline: 1.2086x; 1.1601x over previous
//
#include <hip/hip_runtime.h>
#include <hip/hip_bf16.h>
#include <stdint.h>

#define H_ 12
#define D_ 32
#define N_ 49
#define C_ 384
#define B_TOT 2048
#define BH 24576            // B_TOT * H_
#define M_ROWS 100352       // B_TOT * N_
#define SCALE 0.17677669529663689f

typedef float f32x4 __attribute__((ext_vector_type(4)));
typedef __bf16 bf16x8 __attribute__((ext_vector_type(8)));
typedef unsigned short ushortx8 __attribute__((ext_vector_type(8)));

static __device__ __forceinline__ unsigned short f2bf(float f) {
  __bf16 b = (__bf16)f;
  return __builtin_bit_cast(unsigned short, b);
}

// ---------------------------------------------------------------------------
// K-1: fp32 -> bf16 cast, 8 elems/thread, grid-stride
// ---------------------------------------------------------------------------
__global__ void cast_bf16(const float* __restrict__ in,
                          unsigned short* __restrict__ out, int n8) {
  int i = blockIdx.x * blockDim.x + threadIdx.x;
  const int stride = gridDim.x * blockDim.x;
  for (; i < n8; i += stride) {
    float4 a = ((const float4*)in)[2 * i];
    float4 b = ((const float4*)in)[2 * i + 1];
    ushortx8 v;
    v[0] = f2bf(a.x); v[1] = f2bf(a.y); v[2] = f2bf(a.z); v[3] = f2bf(a.w);
    v[4] = f2bf(b.x); v[5] = f2bf(b.y); v[6] = f2bf(b.z); v[7] = f2bf(b.w);
    *(ushortx8*)&out[(size_t)i * 8] = v;
  }
}

// ---------------------------------------------------------------------------
// K0: combined bias+mask table: comb[w][h][64][64], -1e30 at c>=49 (mask pad)
// ---------------------------------------------------------------------------
__global__ void build_comb(const float* __restrict__ mask,
                           const float* __restrict__ rpb,
                           const int* __restrict__ ridx,
                           float* __restrict__ comb) {
  const int h = blockIdx.x, w = blockIdx.y;
  float* cb = comb + (size_t)(w * H_ + h) * 4096;
  const float* mw = mask + (size_t)w * N_ * N_;
  for (int e = threadIdx.x; e < 4096; e += 256) {
    const int r = e >> 6, c = e & 63;
    float v;
    if (c >= N_) v = -1e30f;
    else if (r >= N_) v = 0.0f;
    else v = mw[r * N_ + c] + rpb[ridx[r * N_ + c] * H_ + h];
    cb[e] = v;
  }
}

// ---------------------------------------------------------------------------
// K1: QKV GEMM (all-bf16): qkv = x @ qkv_w.T + qkv_b. 128x128 tile, 4 waves.
// XCD-grouped swizzle: all 9 N-tiles of an A-tile on one XCD (L2 reuse).
// Coalesced epilogue: per-wave LDS restage -> 64B-line stores.
// ---------------------------------------------------------------------------
__global__ __launch_bounds__(256, 3)
void qkv_gemm(const unsigned short* __restrict__ A,
              const unsigned short* __restrict__ W,
              const float* __restrict__ bias, unsigned short* __restrict__ qkv) {
  __shared__ __align__(16) unsigned short smem[20480];  // 40 KB
  unsigned short* lA0 = smem;            // [2][128*40]
  unsigned short* lB0 = smem + 10240;    // [2][128*40]
  const int tid = threadIdx.x;
  // XCD group swizzle: 7056 blocks = 8 XCDs x 882; 882 = 98 groups x 9 ntiles
  const int w = blockIdx.x;
  const int t = (w & 7) * 882 + (w >> 3);
  const int bm = t / 9, bn = t - bm * 9;

  const int lane = tid & 63, wv = tid >> 6;
  const int wm = wv >> 1, wn = wv & 1;
  const int lo = lane & 15, hi = lane >> 4;
  const int r0 = tid >> 2, r1 = r0 + 64;
  const int off = (tid & 3) * 8;

  const unsigned short* Ab = A + (size_t)bm * 128 * 384;
  const unsigned short* Wb = W + (size_t)bn * 128 * 384;

  f32x4 acc[4][4];
#pragma unroll
  for (int i = 0; i < 4; i++)
#pragma unroll
    for (int j = 0; j < 4; j++)
#pragma unroll
      for (int r = 0; r < 4; r++) acc[i][j][r] = 0.0f;

  // stage kt=0
  *(uint4*)&lA0[r0 * 40 + off] = *(const uint4*)(Ab + r0 * 384 + off);
  *(uint4*)&lA0[r1 * 40 + off] = *(const uint4*)(Ab + r1 * 384 + off);
  *(uint4*)&lB0[r0 * 40 + off] = *(const uint4*)(Wb + r0 * 384 + off);
  *(uint4*)&lB0[r1 * 40 + off] = *(const uint4*)(Wb + r1 * 384 + off);
  __syncthreads();

  int buf = 0;
  for (int kt = 0; kt < 12; kt++) {
    uint4 pa0, pa1, pb0, pb1;
    if (kt < 11) {
      const int kc = (kt + 1) * 32 + off;
      pa0 = *(const uint4*)(Ab + r0 * 384 + kc);
      pa1 = *(const uint4*)(Ab + r1 * 384 + kc);
      pb0 = *(const uint4*)(Wb + r0 * 384 + kc);
      pb1 = *(const uint4*)(Wb + r1 * 384 + kc);
    }
    const unsigned short* la = lA0 + buf * 5120;
    const unsigned short* lb = lB0 + buf * 5120;
    bf16x8 af[4], bfm[4];
#pragma unroll
    for (int mt = 0; mt < 4; mt++)
      af[mt] = *(const bf16x8*)&la[(wm * 64 + mt * 16 + lo) * 40 + hi * 8];
#pragma unroll
    for (int nt = 0; nt < 4; nt++)
      bfm[nt] = *(const bf16x8*)&lb[(wn * 64 + nt * 16 + lo) * 40 + hi * 8];
#pragma unroll
    for (int mt = 0; mt < 4; mt++)
#pragma unroll
      for (int nt = 0; nt < 4; nt++)
        acc[mt][nt] = __builtin_amdgcn_mfma_f32_16x16x32_bf16(af[mt], bfm[nt], acc[mt][nt], 0, 0, 0);
    if (kt < 11) {
      unsigned short* wa = lA0 + (buf ^ 1) * 5120;
      unsigned short* wb = lB0 + (buf ^ 1) * 5120;
      *(uint4*)&wa[r0 * 40 + off] = pa0;
      *(uint4*)&wa[r1 * 40 + off] = pa1;
      *(uint4*)&wb[r0 * 40 + off] = pb0;
      *(uint4*)&wb[r1 * 40 + off] = pb1;
    }
    __syncthreads();
    buf ^= 1;
  }

  // epilogue: per-wave 64x64 subtile -> LDS chunks of 32 shorts (pad to 40),
  // then full 64B-line stores. Wave-private region: no barrier needed.
  unsigned short* ep = smem + wv * 5120;  // 128 chunks * 40 shorts
#pragma unroll
  for (int nt = 0; nt < 4; nt++) {
    const int j = bn * 128 + wn * 64 + nt * 16 + lo;
    const float bj = bias[j];
    const float mul = (j < 384) ? SCALE : 1.0f;
    const int ch = nt >> 1;
    const int dd = (nt & 1) * 16 + lo;
#pragma unroll
    for (int mt = 0; mt < 4; mt++) {
#pragma unroll
      for (int r = 0; r < 4; r++) {
        const int row = mt * 16 + hi * 4 + r;
        ep[(row * 2 + ch) * 40 + dd] = f2bf((acc[mt][nt][r] + bj) * mul);
      }
    }
  }
#pragma unroll
  for (int cc = 0; cc < 2; cc++) {
    const int cidx = cc * 64 + lane;
    const int lr = cidx >> 1, lch = cidx & 1;
    const int i = bm * 128 + wm * 64 + lr;
    const int b = i / 49, sq = i - b * 49;
    const int j0 = bn * 128 + wn * 64 + lch * 32;
    const int which = j0 / 384;
    const int rem = j0 - which * 384;
    const int h = rem >> 5;
    unsigned short* dst = qkv + ((size_t)which * BH + (size_t)b * H_ + h) * (N_ * D_) + sq * D_;
    const unsigned short* src = ep + cidx * 40;
#pragma unroll
    for (int q = 0; q < 4; q++)
      *(uint4*)(dst + q * 8) = *(const uint4*)(src + q * 8);
  }
}

// ---------------------------------------------------------------------------
// K2: attention per (b,h). 1 wave. QK^T MFMA, +comb, softmax, P/V via LDS,
// PV MFMA. Writes probs fp32 (d_out) and attn@V bf16 (ws, 64B-line stores).
// ---------------------------------------------------------------------------
__global__ __launch_bounds__(64, 2)
void attn_kernel(const unsigned short* __restrict__ qkv,
                 const float* __restrict__ comb,
                 float* __restrict__ probs,
                 unsigned short* __restrict__ av) {
  __shared__ __align__(16) unsigned short P[64 * 72];
  __shared__ __align__(16) unsigned short VT[32 * 72];
  const int lane = threadIdx.x;
  const int lo = lane & 15, hi = lane >> 4;
  const int h = blockIdx.x, b = blockIdx.y;

  const unsigned short* qp = qkv + (size_t)(b * H_ + h) * (N_ * D_);
  const unsigned short* kp = qp + (size_t)BH * (N_ * D_);
  const unsigned short* vp = kp + (size_t)BH * (N_ * D_);

  // zero VT (pad cols must be non-NaN)
  {
    unsigned int* vz = (unsigned int*)VT;
#pragma unroll
    for (int i = 0; i < 18; i++) vz[lane + 64 * i] = 0u;
  }
  __syncthreads();

  // q/k fragments (rows >=49 read adjacent plane: finite, masked later)
  bf16x8 aq[4], bk[4];
#pragma unroll
  for (int t = 0; t < 4; t++) {
    aq[t] = *(const bf16x8*)(qp + (t * 16 + lo) * D_ + hi * 8);
    bk[t] = *(const bf16x8*)(kp + (t * 16 + lo) * D_ + hi * 8);
  }
  f32x4 s[4][4];
#pragma unroll
  for (int mt = 0; mt < 4; mt++)
#pragma unroll
    for (int nt = 0; nt < 4; nt++) {
#pragma unroll
      for (int r = 0; r < 4; r++) s[mt][nt][r] = 0.0f;
      s[mt][nt] = __builtin_amdgcn_mfma_f32_16x16x32_bf16(aq[mt], bk[nt], s[mt][nt], 0, 0, 0);
    }

  // stage V transposed into VT[d][seq]
#pragma unroll
  for (int it = 0; it < 4; it++) {
    const int idx = it * 64 + lane;
    if (idx < 196) {
      const int sq = idx >> 2, ch = idx & 3;
      ushortx8 vv = *(const ushortx8*)(vp + sq * D_ + ch * 8);
#pragma unroll
      for (int jj = 0; jj < 8; jj++) VT[(ch * 8 + jj) * 72 + sq] = vv[jj];
    }
  }

  // + comb, softmax over c (c>=49 pre-masked with -1e30)
  const float* cb = comb + (size_t)((b & 63) * H_ + h) * 4096;
#pragma unroll
  for (int mt = 0; mt < 4; mt++) {
#pragma unroll
    for (int r = 0; r < 4; r++) {
      const int row = mt * 16 + hi * 4 + r;
      const float* crow = cb + row * 64 + lo;
      float v0 = s[mt][0][r] + crow[0];
      float v1 = s[mt][1][r] + crow[16];
      float v2 = s[mt][2][r] + crow[32];
      float v3 = s[mt][3][r] + crow[48];
      float m = fmaxf(fmaxf(v0, v1), fmaxf(v2, v3));
      m = fmaxf(m, __shfl_xor(m, 1));
      m = fmaxf(m, __shfl_xor(m, 2));
      m = fmaxf(m, __shfl_xor(m, 4));
      m = fmaxf(m, __shfl_xor(m, 8));
      v0 = __expf(v0 - m); v1 = __expf(v1 - m);
      v2 = __expf(v2 - m); v3 = __expf(v3 - m);
      float sum = v0 + v1 + v2 + v3;
      sum += __shfl_xor(sum, 1);
      sum += __shfl_xor(sum, 2);
      sum += __shfl_xor(sum, 4);
      sum += __shfl_xor(sum, 8);
      const float rinv = 1.0f / sum;
      s[mt][0][r] = v0 * rinv; s[mt][1][r] = v1 * rinv;
      s[mt][2][r] = v2 * rinv; s[mt][3][r] = v3 * rinv;
    }
  }

  // write probs (fp32) and P (bf16 LDS)
  const size_t pbase = (size_t)(b * H_ + h) * N_ * N_;
#pragma unroll
  for (int mt = 0; mt < 4; mt++) {
#pragma unroll
    for (int r = 0; r < 4; r++) {
      const int row = mt * 16 + hi * 4 + r;
      if (row < N_) {
#pragma unroll
        for (int nt = 0; nt < 4; nt++) {
          const int c = nt * 16 + lo;
          if (c < N_) probs[pbase + row * N_ + c] = s[mt][nt][r];
        }
      }
#pragma unroll
      for (int nt = 0; nt < 4; nt++)
        P[row * 72 + nt * 16 + lo] = f2bf(s[mt][nt][r]);
    }
  }
  __syncthreads();

  // PV: out[qr][dv] = sum_k P[qr][k] * VT[dv][k]
  f32x4 o[4][2];
#pragma unroll
  for (int mt = 0; mt < 4; mt++)
#pragma unroll
    for (int n2 = 0; n2 < 2; n2++)
#pragma unroll
      for (int r = 0; r < 4; r++) o[mt][n2][r] = 0.0f;
#pragma unroll
  for (int ks = 0; ks < 2; ks++) {
    bf16x8 pa[4], vb[2];
#pragma unroll
    for (int mt = 0; mt < 4; mt++)
      pa[mt] = *(const bf16x8*)&P[(mt * 16 + lo) * 72 + ks * 32 + hi * 8];
#pragma unroll
    for (int n2 = 0; n2 < 2; n2++)
      vb[n2] = *(const bf16x8*)&VT[(n2 * 16 + lo) * 72 + ks * 32 + hi * 8];
#pragma unroll
    for (int mt = 0; mt < 4; mt++)
#pragma unroll
      for (int n2 = 0; n2 < 2; n2++)
        o[mt][n2] = __builtin_amdgcn_mfma_f32_16x16x32_bf16(pa[mt], vb[n2], o[mt][n2], 0, 0, 0);
  }

  // restage O in LDS (reuse P), then full 64B-line stores to av
  __syncthreads();
#pragma unroll
  for (int mt = 0; mt < 4; mt++) {
#pragma unroll
    for (int r = 0; r < 4; r++) {
      const int row = mt * 16 + hi * 4 + r;
      if (row < N_) {
#pragma unroll
        for (int n2 = 0; n2 < 2; n2++)
          P[row * 40 + n2 * 16 + lo] = f2bf(o[mt][n2][r]);
      }
    }
  }
  if (lane < N_) {
    unsigned short* dst = av + ((size_t)b * N_ + lane) * C_ + h * D_;
    const unsigned short* src = P + lane * 40;
#pragma unroll
    for (int q = 0; q < 4; q++)
      *(uint4*)(dst + q * 8) = *(const uint4*)(src + q * 8);
  }
}

// ---------------------------------------------------------------------------
// K3: proj GEMM: out = av @ proj_w.T + proj_b. A bf16 [100352][384],
// W bf16 [384][384], out fp32. XCD-grouped swizzle (groups of 3 N-tiles).
// ---------------------------------------------------------------------------
__global__ __launch_bounds__(256, 3)
void proj_gemm(const unsigned short* __restrict__ A,
               const unsigned short* __restrict__ W,
               const float* __restrict__ bias, float* __restrict__ out) {
  __shared__ unsigned short lA[2][128 * 40];
  __shared__ unsigned short lB[2][128 * 40];
  const int tid = threadIdx.x;
  // 2352 blocks = 8 XCDs x 294; 294 = 98 groups x 3 ntiles
  const int w = blockIdx.x;
  const int t = (w & 7) * 294 + (w >> 3);
  const int bm = t / 3, bn = t - bm * 3;
  const int lane = tid & 63, wv = tid >> 6;
  const int wm = wv >> 1, wn = wv & 1;
  const int lo = lane & 15, hi = lane >> 4;
  const int r0 = tid >> 2, r1 = r0 + 64;
  const int off = (tid & 3) * 8;

  const unsigned short* Ab = A + (size_t)bm * 128 * 384;
  const unsigned short* Wb = W + (size_t)bn * 128 * 384;

  f32x4 acc[4][4];
#pragma unroll
  for (int i = 0; i < 4; i++)
#pragma unroll
    for (int j = 0; j < 4; j++)
#pragma unroll
      for (int r = 0; r < 4; r++) acc[i][j][r] = 0.0f;

  *(uint4*)&lA[0][r0 * 40 + off] = *(const uint4*)(Ab + r0 * 384 + off);
  *(uint4*)&lA[0][r1 * 40 + off] = *(const uint4*)(Ab + r1 * 384 + off);
  *(uint4*)&lB[0][r0 * 40 + off] = *(const uint4*)(Wb + r0 * 384 + off);
  *(uint4*)&lB[0][r1 * 40 + off] = *(const uint4*)(Wb + r1 * 384 + off);
  __syncthreads();

  int buf = 0;
  for (int kt = 0; kt < 12; kt++) {
    uint4 pa0, pa1, pb0, pb1;
    if (kt < 11) {
      const int kc = (kt + 1) * 32 + off;
      pa0 = *(const uint4*)(Ab + r0 * 384 + kc);
      pa1 = *(const uint4*)(Ab + r1 * 384 + kc);
      pb0 = *(const uint4*)(Wb + r0 * 384 + kc);
      pb1 = *(const uint4*)(Wb + r1 * 384 + kc);
    }
    bf16x8 af[4], bfm[4];
#pragma unroll
    for (int mt = 0; mt < 4; mt++)
      af[mt] = *(const bf16x8*)&lA[buf][(wm * 64 + mt * 16 + lo) * 40 + hi * 8];
#pragma unroll
    for (int nt = 0; nt < 4; nt++)
      bfm[nt] = *(const bf16x8*)&lB[buf][(wn * 64 + nt * 16 + lo) * 40 + hi * 8];
#pragma unroll
    for (int mt = 0; mt < 4; mt++)
#pragma unroll
      for (int nt = 0; nt < 4; nt++)
        acc[mt][nt] = __builtin_amdgcn_mfma_f32_16x16x32_bf16(af[mt], bfm[nt], acc[mt][nt], 0, 0, 0);
    if (kt < 11) {
      *(uint4*)&lA[buf ^ 1][r0 * 40 + off] = pa0;
      *(uint4*)&lA[buf ^ 1][r1 * 40 + off] = pa1;
      *(uint4*)&lB[buf ^ 1][r0 * 40 + off] = pb0;
      *(uint4*)&lB[buf ^ 1][r1 * 40 + off] = pb1;
    }
    __syncthreads();
    buf ^= 1;
  }

#pragma unroll
  for (int nt = 0; nt < 4; nt++) {
    const int j = bn * 128 + wn * 64 + nt * 16 + lo;
    const float bj = bias[j];
#pragma unroll
    for (int mt = 0; mt < 4; mt++) {
#pragma unroll
      for (int r = 0; r < 4; r++) {
        const int i = bm * 128 + wm * 64 + mt * 16 + hi * 4 + r;
        out[(size_t)i * 384 + j] = acc[mt][nt][r] + bj;
      }
    }
  }
}

// ---------------------------------------------------------------------------
extern "C" void kernel_launch(void* const* d_in, const int* in_sizes, int n_in,
                              void* d_out, int out_size, void* d_ws, size_t ws_size,
                              hipStream_t stream) {
  const float* x      = (const float*)d_in[0];
  const float* mask   = (const float*)d_in[1];
  const float* qkv_w  = (const float*)d_in[2];
  const float* qkv_b  = (const float*)d_in[3];
  const float* proj_w = (const float*)d_in[4];
  const float* proj_b = (const float*)d_in[5];
  const float* rpb    = (const float*)d_in[6];
  const int*   ridx   = (const int*)d_in[7];

  unsigned short* qkv   = (unsigned short*)d_ws;            // 231.2 MB
  unsigned short* av    = qkv + (size_t)3 * BH * N_ * D_;   // alias: x_bf16
  unsigned short* x_bf  = av;
  float* comb           = (float*)(av + (size_t)M_ROWS * C_);
  unsigned short* wq_bf = (unsigned short*)(comb + 768 * 4096);
  unsigned short* wp_bf = wq_bf + 1152 * 384;
  float* out   = (float*)d_out;
  float* probs = out + (size_t)M_ROWS * C_;

  cast_bf16<<<2048, 256, 0, stream>>>(x, x_bf, M_ROWS * C_ / 8);
  cast_bf16<<<216, 256, 0, stream>>>(qkv_w, wq_bf, 1152 * 384 / 8);
  cast_bf16<<<72, 256, 0, stream>>>(proj_w, wp_bf, 384 * 384 / 8);
  build_comb<<<dim3(H_, 64), 256, 0, stream>>>(mask, rpb, ridx, comb);
  qkv_gemm<<<7056, 256, 0, stream>>>(x_bf, wq_bf, qkv_b, qkv);
  attn_kernel<<<dim3(H_, B_TOT), 64, 0, stream>>>(qkv, comb, probs, av);
  proj_gemm<<<2352, 256, 0, stream>>>(av, wp_bf, proj_b, out);
}